// Round 5
// baseline (902.765 us; speedup 1.0000x reference)
//
#include <hip/hip_runtime.h>
#include <math.h>

#define NTHR 512
#define NBLK 512
#define ROWS 65536   // B*S
#define DD   128
#define T_IT 8
#define HALT_TH 0.99f
#define LN_EPS 1e-5f

// output float offsets
#define O1 8388608
#define O2 8454144
#define O3 8519680
#define O4 8585216

// d_ws: only W fp16-split fragments, 393216 bytes. kc_{r,z,c} live in VGPRs.

typedef _Float16 h8 __attribute__((ext_vector_type(8)));
typedef float f4 __attribute__((ext_vector_type(4)));
typedef unsigned long long u64;
typedef u64 u64x2 __attribute__((ext_vector_type(2)));

__device__ __forceinline__ float sigmoidf_(float x) { return 1.0f / (1.0f + expf(-x)); }

__device__ __forceinline__ unsigned short f2bf(float f) {
    unsigned u = __float_as_uint(f);
    u += 0x7FFFu + ((u >> 16) & 1u);   // RNE
    return (unsigned short)(u >> 16);
}
__device__ __forceinline__ float bf2f(unsigned short h) {
    return __uint_as_float(((unsigned)h) << 16);
}

// ---- prep: split W_{r,z,c} (fp32) into fp16 (hi, lo*2048) B-fragments in ws ----
// short index: ((((g*2+half)*2+split)*4+kt)*8+nt)*512 + lane*8 + j
// where krow = half*128 + kt*32 + (lane>>4)*8 + j, n = nt*16 + (lane&15)
__global__ void prep_kernel(const float* __restrict__ Wr, const float* __restrict__ Wz,
                            const float* __restrict__ Wc, _Float16* __restrict__ wsW) {
    int idx = blockIdx.x * 256 + threadIdx.x;
    if (idx >= 98304) return;
    int g = idx >> 15, e = idx & 32767;
    int krow = e >> 7, n = e & 127;
    const float* W = (g == 0) ? Wr : (g == 1) ? Wz : Wc;
    float w = W[(size_t)krow * DD + n];
    _Float16 hi = (_Float16)w;
    _Float16 lo = (_Float16)((w - (float)hi) * 2048.0f);
    int half = krow >> 7, kr = krow & 127;
    int kt = kr >> 5, ko = kr & 31;
    int hh = ko >> 3, j = ko & 7;
    int lane = hh * 16 + (n & 15), nt = n >> 4;
    size_t b0 = ((((size_t)(g*2+half)*2 + 0)*4 + kt)*8 + nt)*512 + lane*8 + j;
    size_t b1 = ((((size_t)(g*2+half)*2 + 1)*4 + kt)*8 + nt)*512 + lane*8 + j;
    wsW[b0] = hi;
    wsW[b1] = lo;
}

__global__ __launch_bounds__(NTHR, 2)
void lru_main(const float* __restrict__ c_kv,
              const float* __restrict__ b_r, const float* __restrict__ b_z,
              const float* __restrict__ b_c,
              const float* __restrict__ W_h, const float* __restrict__ b_h,
              const float* __restrict__ ln_g, const float* __restrict__ ln_b,
              float* __restrict__ out, const _Float16* __restrict__ wsW)
{
    // W double-buffer: [slot][split][kt][nt][lane][j] = 128 KB
    __shared__ _Float16 WB[2][2][4][8][64][8];
    // per-wave A bounce: [wave][split][lane][j] = 16 KB (one kt at a time)
    __shared__ _Float16 AB[8][2][64][8];

    const int tid = threadIdx.x;
    const int w = tid >> 6, l = tid & 63;
    const int lg = l >> 4, lc = l & 15;
    const int rowbase = blockIdx.x * 128 + w * 16;

    // state = c_kv
    float st[4][8];
    {
        const float* cb = c_kv + (size_t)(rowbase + lg*4)*DD + lc;
        #pragma unroll
        for (int q = 0; q < 4; ++q)
            #pragma unroll
            for (int nt = 0; nt < 8; ++nt) st[q][nt] = cb[q*DD + nt*16];
    }

    u64x2 ld[8];
    auto issue = [&](int g, int h) {
        const u64x2* src = (const u64x2*)wsW + (size_t)(g*2 + h)*4096 + tid;
        #pragma unroll
        for (int r = 0; r < 8; ++r) ld[r] = src[(size_t)r * 512];
    };
    auto commit = [&](int slot) {
        u64x2* dst = (u64x2*)&WB[slot][0][0][0][0][0] + tid;
        #pragma unroll
        for (int r = 0; r < 8; ++r) dst[(size_t)r * 512] = ld[r];
    };

    // split v into fp16 (hi, lo*2048) A-fragments via per-kt LDS bounce
    auto bounce = [&](float v[4][8], h8* Fh, h8* Fl) {
        #pragma unroll
        for (int kt = 0; kt < 4; ++kt) {
            #pragma unroll
            for (int dnt = 0; dnt < 2; ++dnt) {
                int nt = kt*2 + dnt;
                int hh = dnt*2 + (lc >> 3);
                int j = lc & 7;
                #pragma unroll
                for (int q = 0; q < 4; ++q) {
                    float vv = v[q][nt];
                    _Float16 vh = (_Float16)vv;
                    _Float16 vl = (_Float16)((vv - (float)vh) * 2048.0f);
                    AB[w][0][hh*16 + lg*4 + q][j] = vh;
                    AB[w][1][hh*16 + lg*4 + q][j] = vl;
                }
            }
            __threadfence_block();
            Fh[kt] = *(h8*)&AB[w][0][l][0];
            Fl[kt] = *(h8*)&AB[w][1][l][0];
            __threadfence_block();
        }
    };

    // u = A @ W[slot] + C(kc regs or 0), fp32-emulated: hh + (h*l + l*h)/2048
    auto matmul = [&](const h8* Fh, const h8* Fl, int slot, const f4* kc, f4* u) {
        const f4 zz = {0.f, 0.f, 0.f, 0.f};
        #pragma unroll
        for (int nt = 0; nt < 8; ++nt) {
            f4 am = kc ? kc[nt] : zz;
            f4 ac = zz;
            #pragma unroll
            for (int kt = 0; kt < 4; ++kt) {
                h8 wh = *(h8*)&WB[slot][0][kt][nt][l][0];
                h8 wl = *(h8*)&WB[slot][1][kt][nt][l][0];
                am = __builtin_amdgcn_mfma_f32_16x16x32_f16(Fh[kt], wh, am, 0, 0, 0);
                ac = __builtin_amdgcn_mfma_f32_16x16x32_f16(Fh[kt], wl, ac, 0, 0, 0);
                ac = __builtin_amdgcn_mfma_f32_16x16x32_f16(Fl[kt], wh, ac, 0, 0, 0);
            }
            u[nt] = am + ac * 4.8828125e-4f;   // + corr/2048
        }
    };

    // kc accumulators (stay in VGPRs for the whole kernel)
    f4 kcR_[8], kcZ_[8], kcC_[8];

    // c_kv fragments (held through the 3 kc phases)
    h8 ckFh[4], ckFl[4];
    bounce(st, ckFh, ckFl);

    issue(0, 1); commit(0); __syncthreads();
    int cur = 0;
    f4 u[8];

    // kc_r = c_kv @ W_r[128:] + b_r
    matmul(ckFh, ckFl, cur, nullptr, u);
    issue(1, 1);
    #pragma unroll
    for (int nt = 0; nt < 8; ++nt) {
        float bb = b_r[nt*16 + lc];
        #pragma unroll
        for (int q = 0; q < 4; ++q) kcR_[nt][q] = u[nt][q] + bb;
    }
    commit(cur ^ 1); __syncthreads(); cur ^= 1;
    // kc_z
    matmul(ckFh, ckFl, cur, nullptr, u);
    issue(2, 1);
    #pragma unroll
    for (int nt = 0; nt < 8; ++nt) {
        float bb = b_z[nt*16 + lc];
        #pragma unroll
        for (int q = 0; q < 4; ++q) kcZ_[nt][q] = u[nt][q] + bb;
    }
    commit(cur ^ 1); __syncthreads(); cur ^= 1;
    // kc_c
    matmul(ckFh, ckFl, cur, nullptr, u);
    issue(0, 0);
    #pragma unroll
    for (int nt = 0; nt < 8; ++nt) {
        float bb = b_c[nt*16 + lc];
        #pragma unroll
        for (int q = 0; q < 4; ++q) kcC_[nt][q] = u[nt][q] + bb;
    }
    commit(cur ^ 1); __syncthreads(); cur ^= 1;

    // ACT state
    float acc_halt[4] = {0,0,0,0}, num_it[4] = {0,0,0,0}, rem[4] = {0,0,0,0};
    float active[4] = {1,1,1,1};
    unsigned ao[4][4] = {};   // acc_out packed bf16 pairs (threshold 0.19 >> bf16 rounding)
    const float bh = b_h[0];

    h8 stFh[4], stFl[4];
    f4 uz[8];

    for (int t = 0; t < T_IT; ++t) {
        const bool is_last = (t == T_IT - 1);

        // intermediates[t-1]: st currently holds the (t-1) output state.
        // Issued right AFTER a barrier so the whole phase-r covers store retirement.
        if (t > 0) {
            float* ib = out + (size_t)O4 + (((size_t)(t-1))*ROWS + rowbase + lg*4)*DD + lc;
            #pragma unroll
            for (int q = 0; q < 4; ++q)
                #pragma unroll
                for (int nt = 0; nt < 8; ++nt) ib[q*DD + nt*16] = st[q][nt];
        }

        // ---- phase r ----
        bounce(st, stFh, stFl);
        matmul(stFh, stFl, cur, kcR_, u);
        issue(1, 0);
        float rs[4][8];
        #pragma unroll
        for (int nt = 0; nt < 8; ++nt)
            #pragma unroll
            for (int q = 0; q < 4; ++q)
                rs[q][nt] = sigmoidf_(u[nt][q]) * st[q][nt];
        commit(cur ^ 1); __syncthreads(); cur ^= 1;

        // ---- phase z (reuses state frags) ----
        matmul(stFh, stFl, cur, kcZ_, uz);
        issue(2, 0);
        commit(cur ^ 1); __syncthreads(); cur ^= 1;

        // ---- phase c ----
        h8 rsFh[4], rsFl[4];
        bounce(rs, rsFh, rsFl);
        matmul(rsFh, rsFl, cur, kcC_, u);
        if (!is_last) issue(0, 0);

        // st' = (1-z)*st + z*tanh(uc)
        #pragma unroll
        for (int nt = 0; nt < 8; ++nt)
            #pragma unroll
            for (int q = 0; q < 4; ++q) {
                float z = sigmoidf_(uz[nt][q]);
                float h = tanhf(u[nt][q]);
                st[q][nt] = (1.0f - z)*st[q][nt] + z*h;
            }

        // LayerNorm, two-pass like reference
        #pragma unroll
        for (int q = 0; q < 4; ++q) {
            float s = 0.f;
            #pragma unroll
            for (int nt = 0; nt < 8; ++nt) s += st[q][nt];
            s += __shfl_xor(s, 1); s += __shfl_xor(s, 2);
            s += __shfl_xor(s, 4); s += __shfl_xor(s, 8);
            float mu = s * (1.0f/128.0f);
            float s2 = 0.f;
            #pragma unroll
            for (int nt = 0; nt < 8; ++nt) { float d = st[q][nt] - mu; s2 += d*d; }
            s2 += __shfl_xor(s2, 1); s2 += __shfl_xor(s2, 2);
            s2 += __shfl_xor(s2, 4); s2 += __shfl_xor(s2, 8);
            float var = s2 * (1.0f/128.0f);
            float rsd = 1.0f / sqrtf(var + LN_EPS);
            #pragma unroll
            for (int nt = 0; nt < 8; ++nt) {
                int d = nt*16 + lc;
                st[q][nt] = (st[q][nt] - mu)*rsd*ln_g[d] + ln_b[d];
            }
        }

        // halt + ACT
        #pragma unroll
        for (int q = 0; q < 4; ++q) {
            float hs = 0.f;
            #pragma unroll
            for (int nt = 0; nt < 8; ++nt) hs += st[q][nt] * W_h[nt*16 + lc];
            hs += __shfl_xor(hs, 1); hs += __shfl_xor(hs, 2);
            hs += __shfl_xor(hs, 4); hs += __shfl_xor(hs, 8);
            float halt    = sigmoidf_(hs + bh);
            float af      = active[q];
            float new_acc = acc_halt[q] + halt*af;
            float w_last  = 1.0f - acc_halt[q];
            bool  halting = (new_acc >= HALT_TH) && (af > 0.5f);
            float w_mid   = halting ? w_last : halt*af;
            float weight  = is_last ? w_last : w_mid;
            rem[q] = is_last ? w_last : (halting ? w_mid : rem[q]);
            float new_act = is_last ? af : (halting ? 0.0f : af);
            #pragma unroll
            for (int p = 0; p < 4; ++p) {
                unsigned pk = ao[q][p];
                float a0 = bf2f((unsigned short)(pk & 0xffffu)) + weight*st[q][2*p];
                float a1 = bf2f((unsigned short)(pk >> 16))     + weight*st[q][2*p+1];
                ao[q][p] = (unsigned)f2bf(a0) | ((unsigned)f2bf(a1) << 16);
            }
            acc_halt[q] = fminf(new_acc, 1.0f);
            num_it[q] += new_act;
            active[q] = new_act;
        }

        if (!is_last) commit(cur ^ 1);
        __syncthreads(); cur ^= 1;
    }

    // intermediates[7]
    {
        float* ib = out + (size_t)O4 + (7ull*ROWS + rowbase + lg*4)*DD + lc;
        #pragma unroll
        for (int q = 0; q < 4; ++q)
            #pragma unroll
            for (int nt = 0; nt < 8; ++nt) ib[q*DD + nt*16] = st[q][nt];
    }

    // final outputs
    {
        float* ob = out + (size_t)(rowbase + lg*4)*DD + lc;
        #pragma unroll
        for (int q = 0; q < 4; ++q)
            #pragma unroll
            for (int p = 0; p < 4; ++p) {
                unsigned pk = ao[q][p];
                ob[q*DD + (2*p)*16]   = bf2f((unsigned short)(pk & 0xffffu));
                ob[q*DD + (2*p+1)*16] = bf2f((unsigned short)(pk >> 16));
            }
    }
    if (lc == 0) {
        #pragma unroll
        for (int q = 0; q < 4; ++q) {
            int rg = rowbase + lg*4 + q;
            out[O1 + rg] = acc_halt[q];
            out[O2 + rg] = num_it[q] + 1.0f;
            out[O3 + rg] = rem[q];
        }
    }
}

extern "C" void kernel_launch(void* const* d_in, const int* in_sizes, int n_in,
                              void* d_out, int out_size, void* d_ws, size_t ws_size,
                              hipStream_t stream) {
    const float* c_kv = (const float*)d_in[0];
    const float* W_r  = (const float*)d_in[1];
    const float* b_r  = (const float*)d_in[2];
    const float* W_z  = (const float*)d_in[3];
    const float* b_z  = (const float*)d_in[4];
    const float* W_c  = (const float*)d_in[5];
    const float* b_c  = (const float*)d_in[6];
    const float* W_h  = (const float*)d_in[7];
    const float* b_h  = (const float*)d_in[8];
    const float* ln_g = (const float*)d_in[9];
    const float* ln_b = (const float*)d_in[10];
    float* out = (float*)d_out;
    _Float16* wsW = (_Float16*)d_ws;

    prep_kernel<<<384, 256, 0, stream>>>(W_r, W_z, W_c, wsW);
    lru_main<<<NBLK, NTHR, 0, stream>>>(c_kv, b_r, b_z, b_c, W_h, b_h,
                                        ln_g, ln_b, out, wsW);
}

// Round 6
// 899.532 us; speedup vs baseline: 1.0036x; 1.0036x over previous
//
#include <hip/hip_runtime.h>
#include <math.h>

#define NTHR 512
#define NBLK 512
#define ROWS 65536   // B*S
#define DD   128
#define T_IT 8
#define HALT_TH 0.99f
#define LN_EPS 1e-5f

// output float offsets
#define O1 8388608
#define O2 8454144
#define O3 8519680
#define O4 8585216

// d_ws: only W fp16-split fragments, 393216 bytes. kc_{r,z,c} live in VGPRs.

typedef _Float16 h8 __attribute__((ext_vector_type(8)));
typedef float f4 __attribute__((ext_vector_type(4)));
typedef unsigned long long u64;
typedef u64 u64x2 __attribute__((ext_vector_type(2)));

__device__ __forceinline__ float sigmoidf_(float x) { return 1.0f / (1.0f + expf(-x)); }

__device__ __forceinline__ unsigned short f2bf(float f) {
    unsigned u = __float_as_uint(f);
    u += 0x7FFFu + ((u >> 16) & 1u);   // RNE
    return (unsigned short)(u >> 16);
}
__device__ __forceinline__ float bf2f(unsigned short h) {
    return __uint_as_float(((unsigned)h) << 16);
}

// ---- prep: split W_{r,z,c} (fp32) into fp16 (hi, lo*2048) B-fragments in ws ----
// short index: ((((g*2+half)*2+split)*4+kt)*8+nt)*512 + lane*8 + j
// where krow = half*128 + kt*32 + (lane>>4)*8 + j, n = nt*16 + (lane&15)
__global__ void prep_kernel(const float* __restrict__ Wr, const float* __restrict__ Wz,
                            const float* __restrict__ Wc, _Float16* __restrict__ wsW) {
    int idx = blockIdx.x * 256 + threadIdx.x;
    if (idx >= 98304) return;
    int g = idx >> 15, e = idx & 32767;
    int krow = e >> 7, n = e & 127;
    const float* W = (g == 0) ? Wr : (g == 1) ? Wz : Wc;
    float w = W[(size_t)krow * DD + n];
    _Float16 hi = (_Float16)w;
    _Float16 lo = (_Float16)((w - (float)hi) * 2048.0f);
    int half = krow >> 7, kr = krow & 127;
    int kt = kr >> 5, ko = kr & 31;
    int hh = ko >> 3, j = ko & 7;
    int lane = hh * 16 + (n & 15), nt = n >> 4;
    size_t b0 = ((((size_t)(g*2+half)*2 + 0)*4 + kt)*8 + nt)*512 + lane*8 + j;
    size_t b1 = ((((size_t)(g*2+half)*2 + 1)*4 + kt)*8 + nt)*512 + lane*8 + j;
    wsW[b0] = hi;
    wsW[b1] = lo;
}

// split V (name of float[4][8]) into fp16 hi/lo A-fragments FH/FL (names of h8[4])
#define BOUNCE(V, FH, FL) do {                                                  \
    _Pragma("unroll")                                                           \
    for (int kt = 0; kt < 4; ++kt) {                                            \
        _Pragma("unroll")                                                       \
        for (int dnt = 0; dnt < 2; ++dnt) {                                     \
            int nt = kt*2 + dnt;                                                \
            int hh = dnt*2 + (lc >> 3);                                         \
            int j = lc & 7;                                                     \
            _Pragma("unroll")                                                   \
            for (int q = 0; q < 4; ++q) {                                       \
                float vv = V[q][nt];                                            \
                _Float16 vh = (_Float16)vv;                                     \
                _Float16 vl = (_Float16)((vv - (float)vh) * 2048.0f);           \
                AB[w][0][hh*16 + lg*4 + q][j] = vh;                             \
                AB[w][1][hh*16 + lg*4 + q][j] = vl;                             \
            }                                                                   \
        }                                                                       \
        __threadfence_block();                                                  \
        FH[kt] = *(h8*)&AB[w][0][l][0];                                        \
        FL[kt] = *(h8*)&AB[w][1][l][0];                                        \
        __threadfence_block();                                                  \
    } } while (0)

// fp32-emulated matmul: uu = KC[nt] + A@W[slot]; EPILOG consumes f4 uu at each nt.
// KC is an array NAME (static index); FH/FL are array names.
#define MATMUL_KC(FH, FL, slot, KC, EPILOG) do {                                \
    _Pragma("unroll")                                                           \
    for (int nt = 0; nt < 8; ++nt) {                                            \
        f4 am = KC[nt];                                                         \
        f4 ac = {0.f, 0.f, 0.f, 0.f};                                           \
        _Pragma("unroll")                                                       \
        for (int kt = 0; kt < 4; ++kt) {                                        \
            h8 wh = *(h8*)&WB[slot][0][kt][nt][l][0];                           \
            h8 wl = *(h8*)&WB[slot][1][kt][nt][l][0];                           \
            am = __builtin_amdgcn_mfma_f32_16x16x32_f16(FH[kt], wh, am, 0,0,0); \
            ac = __builtin_amdgcn_mfma_f32_16x16x32_f16(FH[kt], wl, ac, 0,0,0); \
            ac = __builtin_amdgcn_mfma_f32_16x16x32_f16(FL[kt], wh, ac, 0,0,0); \
        }                                                                       \
        f4 uu = am + ac * 4.8828125e-4f;                                        \
        EPILOG;                                                                 \
    } } while (0)

// same but zero C-init (for kc precompute)
#define MATMUL_Z(FH, FL, slot, EPILOG) do {                                     \
    _Pragma("unroll")                                                           \
    for (int nt = 0; nt < 8; ++nt) {                                            \
        f4 am = {0.f, 0.f, 0.f, 0.f};                                           \
        f4 ac = {0.f, 0.f, 0.f, 0.f};                                           \
        _Pragma("unroll")                                                       \
        for (int kt = 0; kt < 4; ++kt) {                                        \
            h8 wh = *(h8*)&WB[slot][0][kt][nt][l][0];                           \
            h8 wl = *(h8*)&WB[slot][1][kt][nt][l][0];                           \
            am = __builtin_amdgcn_mfma_f32_16x16x32_f16(FH[kt], wh, am, 0,0,0); \
            ac = __builtin_amdgcn_mfma_f32_16x16x32_f16(FH[kt], wl, ac, 0,0,0); \
            ac = __builtin_amdgcn_mfma_f32_16x16x32_f16(FL[kt], wh, ac, 0,0,0); \
        }                                                                       \
        f4 uu = am + ac * 4.8828125e-4f;                                        \
        EPILOG;                                                                 \
    } } while (0)

__global__ __launch_bounds__(NTHR, 2)
void lru_main(const float* __restrict__ c_kv,
              const float* __restrict__ b_r, const float* __restrict__ b_z,
              const float* __restrict__ b_c,
              const float* __restrict__ W_h, const float* __restrict__ b_h,
              const float* __restrict__ ln_g, const float* __restrict__ ln_b,
              float* __restrict__ out, const _Float16* __restrict__ wsW)
{
    // W double-buffer: [slot][split][kt][nt][lane][j] = 128 KB
    __shared__ _Float16 WB[2][2][4][8][64][8];
    // per-wave A bounce: [wave][split][lane][j] = 16 KB (one kt at a time)
    __shared__ _Float16 AB[8][2][64][8];

    const int tid = threadIdx.x;
    const int w = tid >> 6, l = tid & 63;
    const int lg = l >> 4, lc = l & 15;
    const int rowbase = blockIdx.x * 128 + w * 16;

    // state = c_kv
    float st[4][8];
    {
        const float* cb = c_kv + (size_t)(rowbase + lg*4)*DD + lc;
        #pragma unroll
        for (int q = 0; q < 4; ++q)
            #pragma unroll
            for (int nt = 0; nt < 8; ++nt) st[q][nt] = cb[q*DD + nt*16];
    }

    u64x2 ld[8];
    auto issue = [&](int g, int h) {
        const u64x2* src = (const u64x2*)wsW + (size_t)(g*2 + h)*4096 + tid;
        #pragma unroll
        for (int r = 0; r < 8; ++r) ld[r] = src[(size_t)r * 512];
    };
    auto commit = [&](int slot) {
        u64x2* dst = (u64x2*)&WB[slot][0][0][0][0][0] + tid;
        #pragma unroll
        for (int r = 0; r < 8; ++r) dst[(size_t)r * 512] = ld[r];
    };

    // kc accumulators — must live in VGPRs (all statically indexed)
    f4 kcR_[8], kcZ_[8], kcC_[8];

    // c_kv fragments (held through the 3 kc phases)
    h8 ckFh[4], ckFl[4];
    BOUNCE(st, ckFh, ckFl);

    issue(0, 1); commit(0); __syncthreads();
    int cur = 0;

    // kc_g = c_kv @ W_g[128:] + b_g
    MATMUL_Z(ckFh, ckFl, cur, { kcR_[nt] = uu + b_r[nt*16 + lc]; });
    issue(1, 1);
    commit(cur ^ 1); __syncthreads(); cur ^= 1;

    MATMUL_Z(ckFh, ckFl, cur, { kcZ_[nt] = uu + b_z[nt*16 + lc]; });
    issue(2, 1);
    commit(cur ^ 1); __syncthreads(); cur ^= 1;

    MATMUL_Z(ckFh, ckFl, cur, { kcC_[nt] = uu + b_c[nt*16 + lc]; });
    issue(0, 0);
    commit(cur ^ 1); __syncthreads(); cur ^= 1;

    // ACT state
    float acc_halt[4] = {0,0,0,0}, num_it[4] = {0,0,0,0}, rem[4] = {0,0,0,0};
    float active[4] = {1,1,1,1};
    unsigned ao[4][4] = {};   // acc_out packed bf16 pairs (threshold 0.19 >> bf16 rounding)
    const float bh = b_h[0];

    h8 stFh[4], stFl[4];
    f4 uz[8];

    for (int t = 0; t < T_IT; ++t) {
        const bool is_last = (t == T_IT - 1);

        // intermediates[t-1]: st currently holds the (t-1) output state.
        // Issued right AFTER a barrier so the whole phase-r covers store retirement.
        if (t > 0) {
            float* ib = out + (size_t)O4 + (((size_t)(t-1))*ROWS + rowbase + lg*4)*DD + lc;
            #pragma unroll
            for (int q = 0; q < 4; ++q)
                #pragma unroll
                for (int nt = 0; nt < 8; ++nt) ib[q*DD + nt*16] = st[q][nt];
        }

        // ---- phase r (epilogue folds sigmoid*st -> rs immediately) ----
        BOUNCE(st, stFh, stFl);
        float rs[4][8];
        MATMUL_KC(stFh, stFl, cur, kcR_, {
            _Pragma("unroll")
            for (int q = 0; q < 4; ++q) rs[q][nt] = sigmoidf_(uu[q]) * st[q][nt];
        });
        issue(1, 0);
        commit(cur ^ 1); __syncthreads(); cur ^= 1;

        // ---- phase z (reuses state frags) ----
        MATMUL_KC(stFh, stFl, cur, kcZ_, { uz[nt] = uu; });
        issue(2, 0);
        commit(cur ^ 1); __syncthreads(); cur ^= 1;

        // ---- phase c (epilogue does the full state update per nt) ----
        h8 rsFh[4], rsFl[4];
        BOUNCE(rs, rsFh, rsFl);
        MATMUL_KC(rsFh, rsFl, cur, kcC_, {
            _Pragma("unroll")
            for (int q = 0; q < 4; ++q) {
                float z = sigmoidf_(uz[nt][q]);
                float h = tanhf(uu[q]);
                st[q][nt] = (1.0f - z)*st[q][nt] + z*h;
            }
        });
        if (!is_last) issue(0, 0);

        // LayerNorm, two-pass like reference
        #pragma unroll
        for (int q = 0; q < 4; ++q) {
            float s = 0.f;
            #pragma unroll
            for (int nt = 0; nt < 8; ++nt) s += st[q][nt];
            s += __shfl_xor(s, 1); s += __shfl_xor(s, 2);
            s += __shfl_xor(s, 4); s += __shfl_xor(s, 8);
            float mu = s * (1.0f/128.0f);
            float s2 = 0.f;
            #pragma unroll
            for (int nt = 0; nt < 8; ++nt) { float d = st[q][nt] - mu; s2 += d*d; }
            s2 += __shfl_xor(s2, 1); s2 += __shfl_xor(s2, 2);
            s2 += __shfl_xor(s2, 4); s2 += __shfl_xor(s2, 8);
            float var = s2 * (1.0f/128.0f);
            float rsd = 1.0f / sqrtf(var + LN_EPS);
            #pragma unroll
            for (int nt = 0; nt < 8; ++nt) {
                int d = nt*16 + lc;
                st[q][nt] = (st[q][nt] - mu)*rsd*ln_g[d] + ln_b[d];
            }
        }

        // halt + ACT
        #pragma unroll
        for (int q = 0; q < 4; ++q) {
            float hs = 0.f;
            #pragma unroll
            for (int nt = 0; nt < 8; ++nt) hs += st[q][nt] * W_h[nt*16 + lc];
            hs += __shfl_xor(hs, 1); hs += __shfl_xor(hs, 2);
            hs += __shfl_xor(hs, 4); hs += __shfl_xor(hs, 8);
            float halt    = sigmoidf_(hs + bh);
            float af      = active[q];
            float new_acc = acc_halt[q] + halt*af;
            float w_last  = 1.0f - acc_halt[q];
            bool  halting = (new_acc >= HALT_TH) && (af > 0.5f);
            float w_mid   = halting ? w_last : halt*af;
            float weight  = is_last ? w_last : w_mid;
            rem[q] = is_last ? w_last : (halting ? w_mid : rem[q]);
            float new_act = is_last ? af : (halting ? 0.0f : af);
            #pragma unroll
            for (int p = 0; p < 4; ++p) {
                unsigned pk = ao[q][p];
                float a0 = bf2f((unsigned short)(pk & 0xffffu)) + weight*st[q][2*p];
                float a1 = bf2f((unsigned short)(pk >> 16))     + weight*st[q][2*p+1];
                ao[q][p] = (unsigned)f2bf(a0) | ((unsigned)f2bf(a1) << 16);
            }
            acc_halt[q] = fminf(new_acc, 1.0f);
            num_it[q] += new_act;
            active[q] = new_act;
        }

        if (!is_last) commit(cur ^ 1);
        __syncthreads(); cur ^= 1;
    }

    // intermediates[7]
    {
        float* ib = out + (size_t)O4 + (7ull*ROWS + rowbase + lg*4)*DD + lc;
        #pragma unroll
        for (int q = 0; q < 4; ++q)
            #pragma unroll
            for (int nt = 0; nt < 8; ++nt) ib[q*DD + nt*16] = st[q][nt];
    }

    // final outputs
    {
        float* ob = out + (size_t)(rowbase + lg*4)*DD + lc;
        #pragma unroll
        for (int q = 0; q < 4; ++q)
            #pragma unroll
            for (int p = 0; p < 4; ++p) {
                unsigned pk = ao[q][p];
                ob[q*DD + (2*p)*16]   = bf2f((unsigned short)(pk & 0xffffu));
                ob[q*DD + (2*p+1)*16] = bf2f((unsigned short)(pk >> 16));
            }
    }
    if (lc == 0) {
        #pragma unroll
        for (int q = 0; q < 4; ++q) {
            int rg = rowbase + lg*4 + q;
            out[O1 + rg] = acc_halt[q];
            out[O2 + rg] = num_it[q] + 1.0f;
            out[O3 + rg] = rem[q];
        }
    }
}

extern "C" void kernel_launch(void* const* d_in, const int* in_sizes, int n_in,
                              void* d_out, int out_size, void* d_ws, size_t ws_size,
                              hipStream_t stream) {
    const float* c_kv = (const float*)d_in[0];
    const float* W_r  = (const float*)d_in[1];
    const float* b_r  = (const float*)d_in[2];
    const float* W_z  = (const float*)d_in[3];
    const float* b_z  = (const float*)d_in[4];
    const float* W_c  = (const float*)d_in[5];
    const float* b_c  = (const float*)d_in[6];
    const float* W_h  = (const float*)d_in[7];
    const float* b_h  = (const float*)d_in[8];
    const float* ln_g = (const float*)d_in[9];
    const float* ln_b = (const float*)d_in[10];
    float* out = (float*)d_out;
    _Float16* wsW = (_Float16*)d_ws;

    prep_kernel<<<384, 256, 0, stream>>>(W_r, W_z, W_c, wsW);
    lru_main<<<NBLK, NTHR, 0, stream>>>(c_kv, b_r, b_z, b_c, W_h, b_h,
                                        ln_g, ln_b, out, wsW);
}

// Round 7
// 857.047 us; speedup vs baseline: 1.0533x; 1.0496x over previous
//
#include <hip/hip_runtime.h>
#include <math.h>

#define NTHR 512
#define NBLK 512
#define ROWS 65536   // B*S
#define DD   128
#define T_IT 8
#define HALT_TH 0.99f
#define LN_EPS 1e-5f

// output float offsets
#define O1 8388608
#define O2 8454144
#define O3 8519680
#define O4 8585216

// d_ws: only W fp16-split fragments, 393216 bytes. kc_{r,z,c} live in VGPRs.

typedef _Float16 h8 __attribute__((ext_vector_type(8)));
typedef float f4 __attribute__((ext_vector_type(4)));

typedef __attribute__((address_space(1))) const unsigned int gau32;
typedef __attribute__((address_space(3))) unsigned int lau32;

__device__ __forceinline__ float sigmoidf_(float x) { return 1.0f / (1.0f + expf(-x)); }

__device__ __forceinline__ unsigned short f2bf(float f) {
    unsigned u = __float_as_uint(f);
    u += 0x7FFFu + ((u >> 16) & 1u);   // RNE
    return (unsigned short)(u >> 16);
}
__device__ __forceinline__ float bf2f(unsigned short h) {
    return __uint_as_float(((unsigned)h) << 16);
}

// ---- prep: split W_{r,z,c} (fp32) into fp16 (hi, lo*2048) B-fragments in ws ----
// short index: ((((g*2+half)*2+split)*4+kt)*8+nt)*512 + lane*8 + j
// where krow = half*128 + kt*32 + (lane>>4)*8 + j, n = nt*16 + (lane&15)
__global__ void prep_kernel(const float* __restrict__ Wr, const float* __restrict__ Wz,
                            const float* __restrict__ Wc, _Float16* __restrict__ wsW) {
    int idx = blockIdx.x * 256 + threadIdx.x;
    if (idx >= 98304) return;
    int g = idx >> 15, e = idx & 32767;
    int krow = e >> 7, n = e & 127;
    const float* W = (g == 0) ? Wr : (g == 1) ? Wz : Wc;
    float w = W[(size_t)krow * DD + n];
    _Float16 hi = (_Float16)w;
    _Float16 lo = (_Float16)((w - (float)hi) * 2048.0f);
    int half = krow >> 7, kr = krow & 127;
    int kt = kr >> 5, ko = kr & 31;
    int hh = ko >> 3, j = ko & 7;
    int lane = hh * 16 + (n & 15), nt = n >> 4;
    size_t b0 = ((((size_t)(g*2+half)*2 + 0)*4 + kt)*8 + nt)*512 + lane*8 + j;
    size_t b1 = ((((size_t)(g*2+half)*2 + 1)*4 + kt)*8 + nt)*512 + lane*8 + j;
    wsW[b0] = hi;
    wsW[b1] = lo;
}

// split fp32 V[4][8] into fp16 hi/lo A-fragments FH/FL (names of h8[4])
#define BOUNCE(V, FH, FL) do {                                                  \
    _Pragma("unroll")                                                           \
    for (int kt = 0; kt < 4; ++kt) {                                            \
        _Pragma("unroll")                                                       \
        for (int dnt = 0; dnt < 2; ++dnt) {                                     \
            int nt = kt*2 + dnt;                                                \
            int hh = dnt*2 + (lc >> 3);                                         \
            int j = lc & 7;                                                     \
            _Pragma("unroll")                                                   \
            for (int q = 0; q < 4; ++q) {                                       \
                float vv = V[q][nt];                                            \
                _Float16 vh = (_Float16)vv;                                     \
                _Float16 vl = (_Float16)((vv - (float)vh) * 2048.0f);           \
                AB[w][0][hh*16 + lg*4 + q][j] = vh;                             \
                AB[w][1][hh*16 + lg*4 + q][j] = vl;                             \
            }                                                                   \
        }                                                                       \
        __threadfence_block();                                                  \
        FH[kt] = *(h8*)&AB[w][0][l][0];                                        \
        FL[kt] = *(h8*)&AB[w][1][l][0];                                        \
        __threadfence_block();                                                  \
    } } while (0)

// same, but from pre-split packed fp16 VH/VL (names of h8[4], indexed [q][nt])
#define BOUNCE_P(VH, VL, FH, FL) do {                                           \
    _Pragma("unroll")                                                           \
    for (int kt = 0; kt < 4; ++kt) {                                            \
        _Pragma("unroll")                                                       \
        for (int dnt = 0; dnt < 2; ++dnt) {                                     \
            int nt = kt*2 + dnt;                                                \
            int hh = dnt*2 + (lc >> 3);                                         \
            int j = lc & 7;                                                     \
            _Pragma("unroll")                                                   \
            for (int q = 0; q < 4; ++q) {                                       \
                AB[w][0][hh*16 + lg*4 + q][j] = VH[q][nt];                      \
                AB[w][1][hh*16 + lg*4 + q][j] = VL[q][nt];                      \
            }                                                                   \
        }                                                                       \
        __threadfence_block();                                                  \
        FH[kt] = *(h8*)&AB[w][0][l][0];                                        \
        FL[kt] = *(h8*)&AB[w][1][l][0];                                        \
        __threadfence_block();                                                  \
    } } while (0)

// fp32-emulated matmul: uu = KC[nt] + A@W[slot]; EPILOG consumes f4 uu at each nt.
#define MATMUL_KC(FH, FL, slot, KC, EPILOG) do {                                \
    _Pragma("unroll")                                                           \
    for (int nt = 0; nt < 8; ++nt) {                                            \
        f4 am = KC[nt];                                                         \
        f4 ac = {0.f, 0.f, 0.f, 0.f};                                           \
        _Pragma("unroll")                                                       \
        for (int kt = 0; kt < 4; ++kt) {                                        \
            h8 wh = *(h8*)&WB[slot][0][kt][nt][l][0];                           \
            h8 wl = *(h8*)&WB[slot][1][kt][nt][l][0];                           \
            am = __builtin_amdgcn_mfma_f32_16x16x32_f16(FH[kt], wh, am, 0,0,0); \
            ac = __builtin_amdgcn_mfma_f32_16x16x32_f16(FH[kt], wl, ac, 0,0,0); \
            ac = __builtin_amdgcn_mfma_f32_16x16x32_f16(FL[kt], wh, ac, 0,0,0); \
        }                                                                       \
        f4 uu = am + ac * 4.8828125e-4f;                                        \
        EPILOG;                                                                 \
    } } while (0)

// same but zero C-init (for kc precompute)
#define MATMUL_Z(FH, FL, slot, EPILOG) do {                                     \
    _Pragma("unroll")                                                           \
    for (int nt = 0; nt < 8; ++nt) {                                            \
        f4 am = {0.f, 0.f, 0.f, 0.f};                                           \
        f4 ac = {0.f, 0.f, 0.f, 0.f};                                           \
        _Pragma("unroll")                                                       \
        for (int kt = 0; kt < 4; ++kt) {                                        \
            h8 wh = *(h8*)&WB[slot][0][kt][nt][l][0];                           \
            h8 wl = *(h8*)&WB[slot][1][kt][nt][l][0];                           \
            am = __builtin_amdgcn_mfma_f32_16x16x32_f16(FH[kt], wh, am, 0,0,0); \
            ac = __builtin_amdgcn_mfma_f32_16x16x32_f16(FH[kt], wl, ac, 0,0,0); \
            ac = __builtin_amdgcn_mfma_f32_16x16x32_f16(FL[kt], wh, ac, 0,0,0); \
        }                                                                       \
        f4 uu = am + ac * 4.8828125e-4f;                                        \
        EPILOG;                                                                 \
    } } while (0)

__global__ __launch_bounds__(NTHR, 1)
void lru_main(const float* __restrict__ c_kv,
              const float* __restrict__ b_r, const float* __restrict__ b_z,
              const float* __restrict__ b_c,
              const float* __restrict__ W_h, const float* __restrict__ b_h,
              const float* __restrict__ ln_g, const float* __restrict__ ln_b,
              float* __restrict__ out, const _Float16* __restrict__ wsW)
{
    // W double-buffer: [slot][split][kt][nt][lane][j] = 128 KB
    __shared__ _Float16 WB[2][2][4][8][64][8];
    // per-wave A bounce: [wave][split][lane][j] = 16 KB (one kt at a time)
    __shared__ _Float16 AB[8][2][64][8];

    const int tid = threadIdx.x;
    const int w = tid >> 6, l = tid & 63;
    const int lg = l >> 4, lc = l & 15;
    const int rowbase = blockIdx.x * 128 + w * 16;

    // async W staging: global -> LDS, 16 B/lane, layouts linear & identical
    auto stage = [&](int g, int h, int slot) {
        const char* gb = (const char*)wsW + ((size_t)(g*2 + h)) * 65536
                       + (size_t)(w*64 + l) * 16;
        char* lb = (char*)&WB[slot][0][0][0][0][0] + (size_t)(w*64 + l) * 16;
        #pragma unroll
        for (int r = 0; r < 8; ++r) {
            __builtin_amdgcn_global_load_lds((gau32*)(gb + r*8192),
                                             (lau32*)(lb + r*8192), 16, 0, 0);
        }
    };

    stage(1, 1, 0);   // W_z kv-half -> slot0 (first kc phase is z)

    // state = c_kv
    float st[4][8];
    {
        const float* cb = c_kv + (size_t)(rowbase + lg*4)*DD + lc;
        #pragma unroll
        for (int q = 0; q < 4; ++q)
            #pragma unroll
            for (int nt = 0; nt < 8; ++nt) st[q][nt] = cb[q*DD + nt*16];
    }

    // kc accumulators — VGPR-resident (all statically indexed)
    f4 kcR_[8], kcZ_[8], kcC_[8];

    h8 ckFh[4], ckFl[4];
    BOUNCE(st, ckFh, ckFl);
    __syncthreads();
    int cur = 0;

    // kc_z = c_kv @ W_z[128:] + b_z
    stage(0, 1, cur ^ 1);
    MATMUL_Z(ckFh, ckFl, cur, { kcZ_[nt] = uu + b_z[nt*16 + lc]; });
    __syncthreads(); cur ^= 1;
    // kc_r
    stage(2, 1, cur ^ 1);
    MATMUL_Z(ckFh, ckFl, cur, { kcR_[nt] = uu + b_r[nt*16 + lc]; });
    __syncthreads(); cur ^= 1;
    // kc_c; prefetch first loop phase (z, state-half)
    stage(1, 0, cur ^ 1);
    MATMUL_Z(ckFh, ckFl, cur, { kcC_[nt] = uu + b_c[nt*16 + lc]; });
    __syncthreads(); cur ^= 1;

    // ACT state
    float acc_halt[4] = {0,0,0,0}, num_it[4] = {0,0,0,0}, rem[4] = {0,0,0,0};
    float active[4] = {1,1,1,1};
    unsigned ao[4][4] = {};   // acc_out packed bf16 pairs (threshold 0.19 >> bf16 rounding)
    const float bh = b_h[0];

    h8 stFh[4], stFl[4];
    h8 rshv[4], rslv[4];      // rs pre-split packed fp16 (16 VGPRs)
    f4 uz[8];

    for (int t = 0; t < T_IT; ++t) {
        const bool is_last = (t == T_IT - 1);

        // intermediates[t-1] issued right after barrier; phase z covers retirement
        if (t > 0) {
            float* ib = out + (size_t)O4 + (((size_t)(t-1))*ROWS + rowbase + lg*4)*DD + lc;
            #pragma unroll
            for (int q = 0; q < 4; ++q)
                #pragma unroll
                for (int nt = 0; nt < 8; ++nt) ib[q*DD + nt*16] = st[q][nt];
        }

        // ---- phase z ----
        stage(0, 0, cur ^ 1);                 // next: r
        BOUNCE(st, stFh, stFl);
        MATMUL_KC(stFh, stFl, cur, kcZ_, { uz[nt] = uu; });
        __syncthreads(); cur ^= 1;

        // ---- phase r (reuses state frags; epilogue folds split(sigmoid*st)) ----
        stage(2, 0, cur ^ 1);                 // next: c
        MATMUL_KC(stFh, stFl, cur, kcR_, {
            _Pragma("unroll")
            for (int q = 0; q < 4; ++q) {
                float rsv = sigmoidf_(uu[q]) * st[q][nt];
                _Float16 vh = (_Float16)rsv;
                rshv[q][nt] = vh;
                rslv[q][nt] = (_Float16)((rsv - (float)vh) * 2048.0f);
            }
        });
        __syncthreads(); cur ^= 1;

        // ---- phase c ----
        if (!is_last) stage(1, 0, cur ^ 1);   // next: z of t+1
        h8 rsFh[4], rsFl[4];
        BOUNCE_P(rshv, rslv, rsFh, rsFl);
        MATMUL_KC(rsFh, rsFl, cur, kcC_, {
            _Pragma("unroll")
            for (int q = 0; q < 4; ++q) {
                float z = sigmoidf_(uz[nt][q]);
                float h = tanhf(uu[q]);
                st[q][nt] = (1.0f - z)*st[q][nt] + z*h;
            }
        });

        // LayerNorm, two-pass like reference
        #pragma unroll
        for (int q = 0; q < 4; ++q) {
            float s = 0.f;
            #pragma unroll
            for (int nt = 0; nt < 8; ++nt) s += st[q][nt];
            s += __shfl_xor(s, 1); s += __shfl_xor(s, 2);
            s += __shfl_xor(s, 4); s += __shfl_xor(s, 8);
            float mu = s * (1.0f/128.0f);
            float s2 = 0.f;
            #pragma unroll
            for (int nt = 0; nt < 8; ++nt) { float d = st[q][nt] - mu; s2 += d*d; }
            s2 += __shfl_xor(s2, 1); s2 += __shfl_xor(s2, 2);
            s2 += __shfl_xor(s2, 4); s2 += __shfl_xor(s2, 8);
            float var = s2 * (1.0f/128.0f);
            float rsd = 1.0f / sqrtf(var + LN_EPS);
            #pragma unroll
            for (int nt = 0; nt < 8; ++nt) {
                int d = nt*16 + lc;
                st[q][nt] = (st[q][nt] - mu)*rsd*ln_g[d] + ln_b[d];
            }
        }

        // halt + ACT
        #pragma unroll
        for (int q = 0; q < 4; ++q) {
            float hs = 0.f;
            #pragma unroll
            for (int nt = 0; nt < 8; ++nt) hs += st[q][nt] * W_h[nt*16 + lc];
            hs += __shfl_xor(hs, 1); hs += __shfl_xor(hs, 2);
            hs += __shfl_xor(hs, 4); hs += __shfl_xor(hs, 8);
            float halt    = sigmoidf_(hs + bh);
            float af      = active[q];
            float new_acc = acc_halt[q] + halt*af;
            float w_last  = 1.0f - acc_halt[q];
            bool  halting = (new_acc >= HALT_TH) && (af > 0.5f);
            float w_mid   = halting ? w_last : halt*af;
            float weight  = is_last ? w_last : w_mid;
            rem[q] = is_last ? w_last : (halting ? w_mid : rem[q]);
            float new_act = is_last ? af : (halting ? 0.0f : af);
            #pragma unroll
            for (int p = 0; p < 4; ++p) {
                unsigned pk = ao[q][p];
                float a0 = bf2f((unsigned short)(pk & 0xffffu)) + weight*st[q][2*p];
                float a1 = bf2f((unsigned short)(pk >> 16))     + weight*st[q][2*p+1];
                ao[q][p] = (unsigned)f2bf(a0) | ((unsigned)f2bf(a1) << 16);
            }
            acc_halt[q] = fminf(new_acc, 1.0f);
            num_it[q] += new_act;
            active[q] = new_act;
        }

        __syncthreads(); cur ^= 1;
    }

    // intermediates[7]
    {
        float* ib = out + (size_t)O4 + (7ull*ROWS + rowbase + lg*4)*DD + lc;
        #pragma unroll
        for (int q = 0; q < 4; ++q)
            #pragma unroll
            for (int nt = 0; nt < 8; ++nt) ib[q*DD + nt*16] = st[q][nt];
    }

    // final outputs
    {
        float* ob = out + (size_t)(rowbase + lg*4)*DD + lc;
        #pragma unroll
        for (int q = 0; q < 4; ++q)
            #pragma unroll
            for (int p = 0; p < 4; ++p) {
                unsigned pk = ao[q][p];
                ob[q*DD + (2*p)*16]   = bf2f((unsigned short)(pk & 0xffffu));
                ob[q*DD + (2*p+1)*16] = bf2f((unsigned short)(pk >> 16));
            }
    }
    if (lc == 0) {
        #pragma unroll
        for (int q = 0; q < 4; ++q) {
            int rg = rowbase + lg*4 + q;
            out[O1 + rg] = acc_halt[q];
            out[O2 + rg] = num_it[q] + 1.0f;
            out[O3 + rg] = rem[q];
        }
    }
}

extern "C" void kernel_launch(void* const* d_in, const int* in_sizes, int n_in,
                              void* d_out, int out_size, void* d_ws, size_t ws_size,
                              hipStream_t stream) {
    const float* c_kv = (const float*)d_in[0];
    const float* W_r  = (const float*)d_in[1];
    const float* b_r  = (const float*)d_in[2];
    const float* W_z  = (const float*)d_in[3];
    const float* b_z  = (const float*)d_in[4];
    const float* W_c  = (const float*)d_in[5];
    const float* b_c  = (const float*)d_in[6];
    const float* W_h  = (const float*)d_in[7];
    const float* b_h  = (const float*)d_in[8];
    const float* ln_g = (const float*)d_in[9];
    const float* ln_b = (const float*)d_in[10];
    float* out = (float*)d_out;
    _Float16* wsW = (_Float16*)d_ws;

    prep_kernel<<<384, 256, 0, stream>>>(W_r, W_z, W_c, wsW);
    lru_main<<<NBLK, NTHR, 0, stream>>>(c_kv, b_r, b_z, b_c, W_h, b_h,
                                        ln_g, ln_b, out, wsW);
}